// Round 9
// baseline (324.724 us; speedup 1.0000x reference)
//
#include <hip/hip_runtime.h>
#include <math.h>
#include <stdint.h>

#define HDIM 128
#define TM 32   // edges per block (4 waves = 2 edge-tiles x 2 feature-halves)

typedef short s16x8 __attribute__((ext_vector_type(8)));      // 8 bf16 (4 VGPRs) MFMA A/B frag
typedef float f32x4 __attribute__((ext_vector_type(4)));      // MFMA C/D frag
typedef unsigned short ushort8 __attribute__((ext_vector_type(8)));

// fp32 -> bf16 round-to-nearest-even
__device__ __forceinline__ unsigned short f2bf(float x) {
    unsigned u = __float_as_uint(x);
    u += 0x7FFFu + ((u >> 16) & 1u);
    return (unsigned short)(u >> 16);
}

// Abramowitz-Stegun 7.1.26: |err| <= 1.5e-7 absolute.
__device__ __forceinline__ float erf_fast(float x) {
    float ax = fabsf(x);
    float t = __builtin_amdgcn_rcpf(fmaf(0.3275911f, ax, 1.0f));
    float p =        fmaf(t, 1.061405429f, -1.453152027f);
    p = fmaf(t, p, 1.421413741f);
    p = fmaf(t, p, -0.284496736f);
    p = fmaf(t, p, 0.254829592f);
    float e = exp2f(ax * ax * -1.4426950408889634f);
    float r = 1.0f - p * t * e;
    return copysignf(r, x);
}

__device__ __forceinline__ float gelu_exact(float x) {
    return 0.5f * x * (1.0f + erf_fast(x * 0.70710678118654752440f));
}

// 16-lane (DPP row) sum via row_ror rotations: full-rate VALU, no LDS pipe.
template <int N>
__device__ __forceinline__ float rot_add(float v) {
    int r = __builtin_amdgcn_update_dpp(0, __float_as_int(v), 0x120 | N, 0xF, 0xF, false);
    return v + __int_as_float(r);
}
__device__ __forceinline__ float row_sum16(float v) {
    v = rot_add<1>(v); v = rot_add<2>(v); v = rot_add<4>(v); v = rot_add<8>(v);
    return v;
}

// async global->LDS 16B per lane; LDS dst must be wave-uniform base + lane*16
__device__ __forceinline__ void async_cp16(void* lds_dst, const void* g_src) {
    __builtin_amdgcn_global_load_lds(
        (const __attribute__((address_space(1))) unsigned int*)g_src,
        (__attribute__((address_space(3))) unsigned int*)lds_dst,
        16, 0, 0);
}

// ---------------- prep (emb convert + W convert + histogram) ----------------
// W1S layout: [g][n][half][h'][8] shorts, half = k/128, h = (k/8)%16, h' = h ^ (n&7).
// W2T[g][n=64][k=128].
__global__ void k_prep(const float* __restrict__ emb, int embElems, int embBlocks,
                       const float* __restrict__ W1, const float* __restrict__ W2,
                       unsigned short* __restrict__ embB,
                       unsigned short* __restrict__ W1S, unsigned short* __restrict__ W2T,
                       const int* __restrict__ groups, int E, int* __restrict__ counts) {
    if ((int)blockIdx.x >= embBlocks + 60) {
        __shared__ int c[3];
        int t = threadIdx.x;
        int blk = blockIdx.x - (embBlocks + 60);
        if (t < 3) c[t] = 0;
        __syncthreads();
        int base = blk * 1024;
        for (int i = t; i < 1024; i += 256) {
            int e = base + i;
            if (e < E) atomicAdd(&c[groups[e]], 1);
        }
        __syncthreads();
        if (t < 3) counts[blk * 3 + t] = c[t];
        return;
    }
    if ((int)blockIdx.x < embBlocks) {
        int i = (blockIdx.x * 256 + threadIdx.x) * 8;
        if (i + 8 <= embElems) {
            float4 a = *(const float4*)(emb + i);
            float4 b = *(const float4*)(emb + i + 4);
            ushort8 o;
            o[0] = f2bf(a.x); o[1] = f2bf(a.y); o[2] = f2bf(a.z); o[3] = f2bf(a.w);
            o[4] = f2bf(b.x); o[5] = f2bf(b.y); o[6] = f2bf(b.z); o[7] = f2bf(b.w);
            *(ushort8*)(embB + i) = o;
        } else {
            for (int j = i; j < embElems; ++j) embB[j] = f2bf(emb[j]);
        }
        return;
    }
    int idx = (blockIdx.x - embBlocks) * 256 + threadIdx.x;
    if (idx < 3 * 32 * 128) {                    // W1S: task = (g, gk, n)
        int g  = idx >> 12;
        int r  = idx & 4095;
        int gk = r >> 7;                         // global k-granule 0..31 (k0 = gk*8)
        int n  = r & 127;
        const float* src = W1 + ((size_t)g * 256 + gk * 8) * 128 + n;
        ushort8 o;
        #pragma unroll
        for (int j = 0; j < 8; ++j) o[j] = f2bf(src[j * 128]);
        int half = gk >> 4;
        int hs   = (gk & 15) ^ (n & 7);          // bank swizzle within half
        *(ushort8*)(W1S + (((size_t)(g * 128 + n) * 2 + half) * 16 + hs) * 8) = o;
    } else if (idx < 3 * 32 * 128 + 3 * 16 * 64) {
        int r2 = idx - 3 * 32 * 128;             // W2T[g][n=64][k=128]
        int g  = r2 >> 10;
        int r  = r2 & 1023;
        int kc = r >> 6;
        int n  = r & 63;
        const float* src = W2 + (size_t)g * 128 * 64 + (size_t)(kc * 8) * 64 + n;
        ushort8 o;
        #pragma unroll
        for (int j = 0; j < 8; ++j) o[j] = f2bf(src[j * 64]);
        *(ushort8*)(W2T + ((size_t)(g * 64 + n)) * 128 + kc * 8) = o;
    }
}

// ---------------- scatter (with fused redundant scan) ----------------
// Each block (1 wave) scans the per-chunk counts itself (6KB, L2-hot), derives its
// bases + group starts, then stable-scatters {u,v} pairs to sorted positions.
__global__ void k_scatter(const int* __restrict__ groups, const int* __restrict__ edges,
                          int E, int nChunks, const int* __restrict__ counts,
                          int* __restrict__ gstart, int2* __restrict__ sortedUV) {
    int b = blockIdx.x;
    int lane = threadIdx.x;  // 64
    int pre0 = 0, pre1 = 0, pre2 = 0, tot0 = 0, tot1 = 0, tot2 = 0;
    for (int base = 0; base < nChunks; base += 64) {
        int c = base + lane;
        int v0 = 0, v1 = 0, v2 = 0;
        if (c < nChunks) { v0 = counts[c*3+0]; v1 = counts[c*3+1]; v2 = counts[c*3+2]; }
        tot0 += v0; tot1 += v1; tot2 += v2;
        if (c < b) { pre0 += v0; pre1 += v1; pre2 += v2; }
    }
    #pragma unroll
    for (int off = 32; off >= 1; off >>= 1) {
        tot0 += __shfl_xor(tot0, off); tot1 += __shfl_xor(tot1, off); tot2 += __shfl_xor(tot2, off);
        pre0 += __shfl_xor(pre0, off); pre1 += __shfl_xor(pre1, off); pre2 += __shfl_xor(pre2, off);
    }
    if (b == 0 && lane == 0) {
        gstart[0] = 0; gstart[1] = tot0; gstart[2] = tot0 + tot1; gstart[3] = E;
    }
    int run0 = pre0;
    int run1 = tot0 + pre1;
    int run2 = tot0 + tot1 + pre2;
    unsigned long long lt = (1ull << lane) - 1ull;
    for (int p = 0; p < 16; ++p) {
        int e = b * 1024 + p * 64 + lane;
        int g = (e < E) ? groups[e] : 3;
        unsigned long long m0 = __ballot(g == 0);
        unsigned long long m1 = __ballot(g == 1);
        unsigned long long m2 = __ballot(g == 2);
        int pos = 0;
        if (g == 0) pos = run0 + __popcll(m0 & lt);
        else if (g == 1) pos = run1 + __popcll(m1 & lt);
        else if (g == 2) pos = run2 + __popcll(m2 & lt);
        if (e < E) {
            int2 uv; uv.x = edges[2 * e]; uv.y = edges[2 * e + 1];
            sortedUV[pos] = uv;
        }
        run0 += __popcll(m0);
        run1 += __popcll(m1);
        run2 += __popcll(m2);
    }
}

// ---------------- fused per-edge MLP (feature-split wave pairs) ----------------
// Block: 256 thr = 4 waves. wave w: edge-tile et=w>>1 (16 edges), feature-half fh=w&1.
// Per wave: GEMM1 acc[4] (16 AGPR), GEMM2 acc2[2] (8 AGPR) -> ~90-100 total regs
// -> 4-5 waves/SIMD. W1 K-split staged 32KB; sH 32x128 bf16 (8KB) + LN/epilogue
// exchange (512B) overlay the dead W1s. Total LDS = 32768 exact.
__global__ __launch_bounds__(256, 4)
void k_mlp(const unsigned short* __restrict__ embB,
           const int2* __restrict__ sortedUV,
           const int* __restrict__ gstart,
           const unsigned short* __restrict__ W1S,
           const float* __restrict__ b1,
           const float* __restrict__ lng, const float* __restrict__ lnb,
           const unsigned short* __restrict__ W2T,
           const float* __restrict__ b2,
           const float* __restrict__ W3, const float* __restrict__ b3,
           float* __restrict__ out, int E)
{
    __shared__ __align__(16) unsigned short smem[16384];   // 32768 B
    unsigned short* W1s = smem;                         // staged half: [128 n][16 gr][8]
    unsigned short* sH  = smem;                         // [32 m][128 c] swizzled (8KB)
    float* sX = (float*)((char*)smem + 8192);           // 128 floats exchange buffer

    const int t    = threadIdx.x;
    const int w    = t >> 6;
    const int et   = w >> 1;        // edge-tile 0..1
    const int fh   = w & 1;         // feature-half 0..1
    const int lane = t & 63;
    const int n0   = lane & 15;     // MFMA 16-index
    const int quad = lane >> 4;     // MFMA k-quad / D row-group

    const int pos0 = blockIdx.x * TM;

    int gs1 = gstart[1], gs2 = gstart[2];
    int plast = (pos0 + TM - 1 < E) ? pos0 + TM - 1 : E - 1;
    int g0 = (pos0  >= gs2) ? 2 : (pos0  >= gs1) ? 1 : 0;
    int g1 = (plast >= gs2) ? 2 : (plast >= gs1) ? 1 : 0;

    // this lane's edge (A-frag row m = n0 within the tile)
    int p_lane = pos0 + et * 16 + n0;
    int pc = p_lane < E ? p_lane : E - 1;
    int2 uv = sortedUV[pc];
    const unsigned short* urow = embB + (size_t)uv.x * HDIM;
    const unsigned short* vrow = embB + (size_t)uv.y * HDIM;

    for (int g = g0; g <= g1; ++g) {
        const unsigned char* W1Sg = (const unsigned char*)(W1S + (size_t)g * 128 * 256);

        // ---- stage half 0 (k 0..127 = u columns), 32KB linear ----
        #pragma unroll
        for (int r = 0; r < 8; ++r)
            async_cp16((unsigned char*)smem + r * 4096 + t * 16,
                       W1Sg + (r * 16 + (t >> 4)) * 512 + (t & 15) * 16);

        s16x8 afr[4];
        #pragma unroll
        for (int ks = 0; ks < 4; ++ks)
            afr[ks] = *(const s16x8*)(urow + ks * 32 + quad * 8);

        f32x4 acc[4];
        #pragma unroll
        for (int nt = 0; nt < 4; ++nt) acc[nt] = (f32x4){0.f, 0.f, 0.f, 0.f};

        // LN constants for this wave's feature-half
        float b1v[4], lgv[4], lbv[4];
        #pragma unroll
        for (int nt = 0; nt < 4; ++nt) {
            int c = (fh * 4 + nt) * 16 + n0;
            b1v[nt] = b1[g * HDIM + c];
            lgv[nt] = lng[g * HDIM + c];
            lbv[nt] = lnb[g * HDIM + c];
        }

        __syncthreads();   // s1: half-0 stage + u A-frags

        #pragma unroll
        for (int ks = 0; ks < 4; ++ks) {
            #pragma unroll
            for (int nt = 0; nt < 4; ++nt) {
                int gk = (ks * 4 + quad) ^ (n0 & 7);
                s16x8 bfrag = *(const s16x8*)(&W1s[((fh * 4 + nt) * 16 + n0) * 128 + gk * 8]);
                acc[nt] = __builtin_amdgcn_mfma_f32_16x16x32_bf16(afr[ks], bfrag, acc[nt], 0, 0, 0);
            }
        }
        __syncthreads();   // s2: half-0 reads done

        // ---- stage half 1 (k 128..255 = v columns) ----
        #pragma unroll
        for (int r = 0; r < 8; ++r)
            async_cp16((unsigned char*)smem + r * 4096 + t * 16,
                       W1Sg + (r * 16 + (t >> 4)) * 512 + 256 + (t & 15) * 16);

        #pragma unroll
        for (int ks = 0; ks < 4; ++ks)
            afr[ks] = *(const s16x8*)(vrow + ks * 32 + quad * 8);

        __syncthreads();   // s3: half-1 stage + v A-frags

        #pragma unroll
        for (int ks = 0; ks < 4; ++ks) {
            #pragma unroll
            for (int nt = 0; nt < 4; ++nt) {
                int gk = (ks * 4 + quad) ^ (n0 & 7);
                s16x8 bfrag = *(const s16x8*)(&W1s[((fh * 4 + nt) * 16 + n0) * 128 + gk * 8]);
                acc[nt] = __builtin_amdgcn_mfma_f32_16x16x32_bf16(afr[ks], bfrag, acc[nt], 0, 0, 0);
            }
        }
        __syncthreads();   // s4: W1s dead -> sH/sX writable

        // ---- LN partials (this feature-half) -> sX ----
        #pragma unroll
        for (int reg = 0; reg < 4; ++reg) {
            float s = 0.f, s2 = 0.f;
            #pragma unroll
            for (int nt = 0; nt < 4; ++nt) {
                float x = acc[nt][reg] + b1v[nt];
                s += x; s2 += x * x;
            }
            s  = row_sum16(s);
            s2 = row_sum16(s2);
            if (n0 == 0) {
                int m = et * 16 + quad * 4 + reg;
                sX[fh * 32 + m]      = s;
                sX[64 + fh * 32 + m] = s2;
            }
        }
        __syncthreads();   // s5: partials visible

        // ---- LN finish + GELU + swizzled sH write ----
        #pragma unroll
        for (int reg = 0; reg < 4; ++reg) {
            int m  = et * 16 + quad * 4 + reg;
            float s  = sX[m] + sX[32 + m];
            float s2 = sX[64 + m] + sX[96 + m];
            float mu  = s  * (1.0f / HDIM);
            float var = s2 * (1.0f / HDIM) - mu * mu;
            float rs  = rsqrtf(var + 1e-5f);
            int mx = m & 7;
            #pragma unroll
            for (int nt = 0; nt < 4; ++nt) {
                float x = acc[nt][reg] + b1v[nt];
                x = (x - mu) * rs * lgv[nt] + lbv[nt];
                x = gelu_exact(x);
                int ntg = fh * 4 + nt;
                int gsw = ((ntg * 2 + (n0 >> 3)) ^ mx) << 3;   // swizzled col granule
                sH[m * 128 + gsw + (n0 & 7)] = f2bf(x);
            }
        }
        __syncthreads();   // s6: sH visible (also: sX re-writable)

        // ---- GEMM2: h[32x128] x W2T cols (this wave's 32 n2) ----
        const unsigned short* W2Tg = W2T + (size_t)g * 64 * 128;
        f32x4 acc2[2];
        #pragma unroll
        for (int nt2 = 0; nt2 < 2; ++nt2) acc2[nt2] = (f32x4){0.f, 0.f, 0.f, 0.f};

        #pragma unroll
        for (int ks2 = 0; ks2 < 4; ++ks2) {
            int m = et * 16 + n0;
            s16x8 a2 = *(const s16x8*)(&sH[m * 128 + (((ks2 * 4 + quad) ^ (m & 7)) << 3)]);
            #pragma unroll
            for (int nt2 = 0; nt2 < 2; ++nt2) {
                int n2 = (fh * 2 + nt2) * 16 + n0;
                s16x8 b2f = *(const s16x8*)(W2Tg + (size_t)n2 * 128 + ks2 * 32 + quad * 8);
                acc2[nt2] = __builtin_amdgcn_mfma_f32_16x16x32_bf16(a2, b2f, acc2[nt2], 0, 0, 0);
            }
        }

        // ---- epilogue: GELU + partial dot W3 -> sX ----
        {
            float b2v[2], w3v[2];
            #pragma unroll
            for (int nt2 = 0; nt2 < 2; ++nt2) {
                int c = (fh * 2 + nt2) * 16 + n0;
                b2v[nt2] = b2[g * 64 + c];
                w3v[nt2] = W3[g * 64 + c];
            }
            #pragma unroll
            for (int reg = 0; reg < 4; ++reg) {
                float sacc = 0.f;
                #pragma unroll
                for (int nt2 = 0; nt2 < 2; ++nt2)
                    sacc += gelu_exact(acc2[nt2][reg] + b2v[nt2]) * w3v[nt2];
                sacc = row_sum16(sacc);
                if (n0 == 0) {
                    int m = et * 16 + quad * 4 + reg;
                    sX[fh * 32 + m] = sacc;
                }
            }
        }
        __syncthreads();   // s7: epilogue partials visible

        if (fh == 0) {
            float bias3 = b3[g];
            int lo = (g == 0) ? 0   : (g == 1) ? gs1 : gs2;
            int hi = (g == 0) ? gs1 : (g == 1) ? gs2 : E;
            #pragma unroll
            for (int reg = 0; reg < 4; ++reg) {
                if (n0 == 0) {
                    int m = et * 16 + quad * 4 + reg;
                    int p = pos0 + m;
                    if (p >= lo && p < hi) out[p] = sX[m] + sX[32 + m] + bias3;
                }
            }
        }
        if (g < g1) __syncthreads();   // s8: only boundary blocks loop again
    }
}

extern "C" void kernel_launch(void* const* d_in, const int* in_sizes, int n_in,
                              void* d_out, int out_size, void* d_ws, size_t ws_size,
                              hipStream_t stream) {
    const float* emb    = (const float*)d_in[0];
    const int*   edges  = (const int*)  d_in[1];
    const int*   groups = (const int*)  d_in[2];
    const float* W1     = (const float*)d_in[3];
    const float* b1     = (const float*)d_in[4];
    const float* lng    = (const float*)d_in[5];
    const float* lnb    = (const float*)d_in[6];
    const float* W2     = (const float*)d_in[7];
    const float* b2     = (const float*)d_in[8];
    const float* W3     = (const float*)d_in[9];
    const float* b3     = (const float*)d_in[10];
    float* out = (float*)d_out;
    int E        = in_sizes[2];
    int embElems = in_sizes[0];

    int nChunks = (E + 1023) / 1024;
    int embBlocks = (embElems / 8 + 255) / 256;

    // workspace layout
    unsigned short* embB = (unsigned short*)d_ws;
    unsigned short* W1S  = embB + (((size_t)embElems + 7) & ~(size_t)7);
    unsigned short* W2T  = W1S + (size_t)3 * 128 * 256;
    int* counts = (int*)(W2T + (size_t)3 * 64 * 128);
    int* gstart = counts + (size_t)nChunks * 3;
    int2* sortedUV = (int2*)(((uintptr_t)(gstart + 4) + 15) & ~(uintptr_t)15);

    k_prep   <<<dim3(embBlocks + 60 + nChunks), dim3(256), 0, stream>>>(
        emb, embElems, embBlocks, W1, W2, embB, W1S, W2T, groups, E, counts);
    k_scatter<<<dim3(nChunks), dim3(64), 0, stream>>>(
        groups, edges, E, nChunks, counts, gstart, sortedUV);

    int nTiles = (E + TM - 1) / TM;
    k_mlp<<<dim3(nTiles), dim3(256), 0, stream>>>(
        embB, sortedUV, gstart, W1S, b1, lng, lnb, W2T, b2, W3, b3, out, E);
}